// Round 8
// baseline (698.875 us; speedup 1.0000x reference)
//
#include <hip/hip_runtime.h>
#include <stdint.h>

typedef __bf16 bf16;
typedef unsigned char u8;
typedef __attribute__((ext_vector_type(8))) __bf16 bf16x8;
typedef __attribute__((ext_vector_type(4))) float f32x4;

#define N_NODES 100000
#define F_IN 165

static inline int cdiv(int a, int b) { return (a + b - 1) / b; }

__device__ __forceinline__ float bfu(unsigned hw) {
  union { unsigned u; float f; } v; v.u = hw << 16; return v.f;
}
__device__ __forceinline__ unsigned packbf2(float a, float b) {
  bf16 x = (bf16)a, y = (bf16)b;
  unsigned short sx = __builtin_bit_cast(unsigned short, x);
  unsigned short sy = __builtin_bit_cast(unsigned short, y);
  return (unsigned)sx | ((unsigned)sy << 16);
}
__device__ __forceinline__ unsigned pk_fp8x4(float a, float b, float c, float d) {
  int v = 0;
  v = __builtin_amdgcn_cvt_pk_fp8_f32(a, b, v, false);
  v = __builtin_amdgcn_cvt_pk_fp8_f32(c, d, v, true);
  return (unsigned)v;
}
__device__ __forceinline__ u8 f32_to_fp8(float v) {
  int t = __builtin_amdgcn_cvt_pk_fp8_f32(v, 0.f, 0, false);
  return (u8)(t & 0xff);
}

__device__ __forceinline__ void async16(const bf16* g, const bf16* l) {
  __builtin_amdgcn_global_load_lds(
      (const __attribute__((address_space(1))) void*)g,
      (__attribute__((address_space(3))) void*)l, 16, 0, 0);
}

// ---------------- edge dtype detection ----------------
__global__ void detect_k(const int* __restrict__ ei32, int* __restrict__ flag) {
  int i = blockIdx.x * 256 + threadIdx.x;  // 65536 samples
  int v = ei32[2 * i + 1];
  if (v != 0) atomicOr(flag, 1);
}

// ---------------- preprocessing (sh: 1 = int64-low-words, 0 = int32) ------
// out-degree histogram (fire-and-forget) + CSR position assignment (staged).
// fillc's final value == in-degree histogram (used by the scan for rowptr).
__global__ void deg_pos_k(const int* __restrict__ ei, int E, const int* __restrict__ flag,
                          int* __restrict__ deg, int* __restrict__ fillc,
                          int2* __restrict__ stage) {
  int e = blockIdx.x * 256 + threadIdx.x;
  if (e >= E) return;
  int sh = (*flag) ? 0 : 1;
  int s = ei[(size_t)e << sh];
  int d = ei[(size_t)(E + e) << sh];
  if ((unsigned)s >= (unsigned)N_NODES || (unsigned)d >= (unsigned)N_NODES || s == d) {
    stage[e] = make_int2(-1, 0);
    return;
  }
  atomicAdd(deg + s, 1);                 // no return needed
  int pos = atomicAdd(fillc + d, 1);
  stage[e] = make_int2(d, pos);
}

__global__ void dinv_k(const int* __restrict__ deg, float* __restrict__ dinv, int n) {
  int i = blockIdx.x * 256 + threadIdx.x;
  if (i >= n) return;
  int dg = deg[i];
  dinv[i] = dg > 0 ? rsqrtf((float)dg) : 0.f;
}

// atomic-free CSR fill from the staged (d,pos) pairs. csr entry = src only.
__global__ void scatter_k(const int* __restrict__ ei, int E, const int* __restrict__ flag,
                          const int* __restrict__ rowptr, const int2* __restrict__ stage,
                          int* __restrict__ csr) {
  int e = blockIdx.x * 256 + threadIdx.x;
  if (e >= E) return;
  int2 st = stage[e];
  if (st.x < 0) return;
  int sh = (*flag) ? 0 : 1;
  int s = ei[(size_t)e << sh];
  csr[rowptr[st.x] + st.y] = s;
}

// ---------------- scans (rowptr from cnt=fillc) ----------------

__global__ void scanA_k(const int* __restrict__ cnt, int* __restrict__ bsum, int nElem) {
  __shared__ int s[256];
  int b = blockIdx.x, t = threadIdx.x;
  int base = b * 1024;
  int sum = 0;
  for (int i = t; i < 1024; i += 256) {
    int idx = base + i;
    sum += (idx < nElem) ? cnt[idx] : 0;
  }
  s[t] = sum; __syncthreads();
  for (int off = 128; off > 0; off >>= 1) {
    if (t < off) s[t] += s[t + off];
    __syncthreads();
  }
  if (t == 0) bsum[b] = s[0];
}

__global__ void scanB_k(int* __restrict__ bsum, int* __restrict__ rowptrN, int nChunk) {
  __shared__ int s[128];
  int t = threadIdx.x;
  int v = (t < nChunk) ? bsum[t] : 0;
  s[t] = v; __syncthreads();
  for (int off = 1; off < 128; off <<= 1) {
    int x = (t >= off) ? s[t - off] : 0;
    __syncthreads();
    s[t] += x;
    __syncthreads();
  }
  int excl = s[t] - v;
  if (t < nChunk) bsum[t] = excl;
  if (t == 127) *rowptrN = s[127];
}

__global__ void scanC_k(const int* __restrict__ cnt, const int* __restrict__ bsum,
                        int* __restrict__ rowptr, int nElem) {
  __shared__ int s[256];
  int b = blockIdx.x, t = threadIdx.x;
  int base = b * 1024 + t * 4;
  int v[4]; int tot = 0;
  for (int i = 0; i < 4; i++) {
    int idx = base + i;
    v[i] = (idx < nElem) ? cnt[idx] : 0;
    tot += v[i];
  }
  s[t] = tot; __syncthreads();
  for (int off = 1; off < 256; off <<= 1) {
    int x = (t >= off) ? s[t - off] : 0;
    __syncthreads();
    s[t] += x;
    __syncthreads();
  }
  int excl = s[t] - tot + bsum[b];
  for (int i = 0; i < 4; i++) {
    int idx = base + i;
    if (idx < nElem) { rowptr[idx] = excl; excl += v[i]; }
  }
}

// ---------------- weight prep ----------------

// W (float): [3][Fin][128].  out (bf16): [384][Kp] = (W0-W2)^T | W1^T | (2W2)^T
__global__ void build_wct_k(const float* __restrict__ W, bf16* __restrict__ out, int Fin, int Kp) {
  int idx = blockIdx.x * 256 + threadIdx.x;
  if (idx >= 384 * Kp) return;
  int r = idx / Kp, k = idx % Kp;
  int t = r >> 7, j = r & 127;
  float v = 0.f;
  if (k < Fin) {
    if (t == 0)
      v = W[(size_t)k * 128 + j] - W[(size_t)2 * Fin * 128 + (size_t)k * 128 + j];
    else if (t == 1)
      v = W[(size_t)Fin * 128 + (size_t)k * 128 + j];
    else
      v = 2.f * W[(size_t)2 * Fin * 128 + (size_t)k * 128 + j];
  }
  out[(size_t)r * Kp + k] = (bf16)v;
}

// pad x (float [N][165]) -> xp (bf16 [N][192], zeros in 165..191)
__global__ void pad_x_k(const float* __restrict__ x, bf16* __restrict__ xp) {
  int idx = blockIdx.x * 256 + threadIdx.x;
  if (idx >= N_NODES * 192) return;
  int n = idx / 192, k = idx % 192;
  xp[idx] = (k < F_IN) ? (bf16)x[(size_t)n * F_IN + k] : (bf16)0.f;
}

// zero the gather pad row (index N_NODES) of both fp8 buffers
__global__ void zero_pads_k(u8* __restrict__ g0, u8* __restrict__ g1) {
  int t = threadIdx.x;  // 128
  g0[(size_t)N_NODES * 128 + t] = 0;
  g1[(size_t)N_NODES * 128 + t] = 0;
}

// ---------------- GEMM: slabs y=0,1 -> bf16 C; slab y=2 -> fp8(dinv[row]*val) ----

__global__ __launch_bounds__(256) void gemm3_k(const bf16* __restrict__ A, int lda,
                                               const bf16* __restrict__ Bt, int K,
                                               bf16* __restrict__ C0, bf16* __restrict__ C1,
                                               u8* __restrict__ C2g,
                                               const float* __restrict__ dinv, int M) {
  __shared__ __align__(16) bf16 As[128 * 32];
  __shared__ __align__(16) bf16 Bs[128 * 32];
  const int tid = threadIdx.x;
  const int w = tid >> 6, l = tid & 63;
  const int mBase = blockIdx.x * 128;
  const int nb = blockIdx.y * 128;
  const int wm = (w >> 1) * 64, wn = (w & 1) * 64;
  const int lr = l & 15, lq = l >> 4;
  f32x4 acc[4][4] = {};
  for (int k0 = 0; k0 < K; k0 += 32) {
#pragma unroll
    for (int p = 0; p < 2; ++p) {
      int q = w * 2 + p;
      int row = q * 16 + (l >> 2);
      int seg = (l & 3) * 8;
      int ar = mBase + row; if (ar > M - 1) ar = M - 1;  // clamp: no OOB reads
      async16(A + (size_t)ar * lda + k0 + seg, &As[q * 512]);
      async16(Bt + (size_t)(nb + row) * K + k0 + seg, &Bs[q * 512]);
    }
    __syncthreads();
    bf16x8 a[4], b[4];
#pragma unroll
    for (int i = 0; i < 4; i++) a[i] = *(const bf16x8*)&As[(wm + i * 16 + lr) * 32 + lq * 8];
#pragma unroll
    for (int j = 0; j < 4; j++) b[j] = *(const bf16x8*)&Bs[(wn + j * 16 + lr) * 32 + lq * 8];
#pragma unroll
    for (int i = 0; i < 4; i++)
#pragma unroll
      for (int j = 0; j < 4; j++)
        acc[i][j] = __builtin_amdgcn_mfma_f32_16x16x32_bf16(a[i], b[j], acc[i][j], 0, 0, 0);
    __syncthreads();
  }
  if (blockIdx.y == 2) {
#pragma unroll
    for (int i = 0; i < 4; i++) {
#pragma unroll
      for (int r = 0; r < 4; r++) {
        int row = mBase + wm + i * 16 + lq * 4 + r;
        if (row < M) {
          float dv = dinv[row];
#pragma unroll
          for (int j = 0; j < 4; j++) {
            int col = wn + j * 16 + lr;
            C2g[(size_t)row * 128 + col] = f32_to_fp8(dv * acc[i][j][r]);
          }
        }
      }
    }
  } else {
    bf16* __restrict__ C = blockIdx.y ? C1 : C0;
#pragma unroll
    for (int i = 0; i < 4; i++) {
#pragma unroll
      for (int r = 0; r < 4; r++) {
        int row = mBase + wm + i * 16 + lq * 4 + r;
        if (row < M) {
#pragma unroll
          for (int j = 0; j < 4; j++) {
            int col = wn + j * 16 + lr;
            C[(size_t)row * 128 + col] = (bf16)acc[i][j][r];
          }
        }
      }
    }
  }
}

// ---------------- sparse propagation (fp8 unweighted gather) ----------------
// One wave per node; half-wave per edge slot; 16 edges per loop body.
// Lane covers 4 features (lc*4..+3) = 4 fp8 bytes per gather.
// Messages pre-scaled by dinv[src] at producers; post-scale by -dinv[n] here.
// MODE 0: t = -dn*sum + addA[n];            write fp8(dn*t) -> out8  (gather-only consumer)
// MODE 1: t = relu(-dn*sum + addA[n]+bias); write bf16 -> outb
// MODE 2: t = -dn*sum + addA[n]+addB[n]+bias; fout = log_softmax(t @ Wl + bl)
template <int MODE>
__global__ __launch_bounds__(256) void prop_k(const int* __restrict__ rowptr,
                                              const int* __restrict__ csr,
                                              const u8* __restrict__ g8,
                                              const float* __restrict__ dinv,
                                              const bf16* __restrict__ addA,
                                              const bf16* __restrict__ addB,
                                              const float* __restrict__ bias,
                                              const float* __restrict__ Wl,
                                              const float* __restrict__ bl,
                                              u8* __restrict__ out8,
                                              bf16* __restrict__ outb,
                                              float* __restrict__ fout) {
  const int n = blockIdx.x * 4 + (threadIdx.x >> 6);
  const int c = threadIdx.x & 63;
  const int half = c >> 5, lc = c & 31;
  const int beg = rowptr[n], end = rowptr[n + 1];
  const u8* __restrict__ gl = g8 + lc * 4;  // lane-fixed feature offset

  float a0 = 0.f, a1 = 0.f, a2 = 0.f, a3 = 0.f;
  for (int e0 = beg; e0 < end; e0 += 16) {
    int sidx[8];
    unsigned g[8];
#pragma unroll
    for (int k = 0; k < 8; k++) {
      int idx = e0 + 2 * k + half;
      sidx[k] = (idx < end) ? csr[idx] : N_NODES;  // pad row = zeros
    }
#pragma unroll
    for (int k = 0; k < 8; k++) g[k] = *(const unsigned*)(gl + (size_t)sidx[k] * 128);
#pragma unroll
    for (int k = 0; k < 8; k++) {
      auto lo = __builtin_amdgcn_cvt_pk_f32_fp8((int)g[k], false);
      auto hi = __builtin_amdgcn_cvt_pk_f32_fp8((int)g[k], true);
      a0 += lo[0]; a1 += lo[1]; a2 += hi[0]; a3 += hi[1];
    }
  }
  const float dn = dinv[n];

  if (MODE == 2) {
    float t0 = -dn * a0, t1 = -dn * a1, t2 = -dn * a2, t3 = -dn * a3;
    if (half == 0) {
      uint2 ua = *(const uint2*)(addA + (size_t)n * 128 + lc * 4);
      uint2 uh = *(const uint2*)(addB + (size_t)n * 128 + lc * 4);
      t0 += bfu(ua.x & 0xffffu) + bfu(uh.x & 0xffffu) + bias[4 * lc + 0];
      t1 += bfu(ua.x >> 16) + bfu(uh.x >> 16) + bias[4 * lc + 1];
      t2 += bfu(ua.y & 0xffffu) + bfu(uh.y & 0xffffu) + bias[4 * lc + 2];
      t3 += bfu(ua.y >> 16) + bfu(uh.y >> 16) + bias[4 * lc + 3];
    }
    float z0 = t0 * Wl[(4 * lc + 0) * 2] + t1 * Wl[(4 * lc + 1) * 2] +
               t2 * Wl[(4 * lc + 2) * 2] + t3 * Wl[(4 * lc + 3) * 2];
    float z1 = t0 * Wl[(4 * lc + 0) * 2 + 1] + t1 * Wl[(4 * lc + 1) * 2 + 1] +
               t2 * Wl[(4 * lc + 2) * 2 + 1] + t3 * Wl[(4 * lc + 3) * 2 + 1];
#pragma unroll
    for (int off = 32; off > 0; off >>= 1) {
      z0 += __shfl_down(z0, off);
      z1 += __shfl_down(z1, off);
    }
    if (c == 0) {
      z0 += bl[0];
      z1 += bl[1];
      float m = fmaxf(z0, z1);
      float lse = m + logf(expf(z0 - m) + expf(z1 - m));
      fout[(size_t)n * 2 + 0] = z0 - lse;
      fout[(size_t)n * 2 + 1] = z1 - lse;
    }
  } else {
    a0 += __shfl_down(a0, 32);
    a1 += __shfl_down(a1, 32);
    a2 += __shfl_down(a2, 32);
    a3 += __shfl_down(a3, 32);
    if (half == 0) {
      uint2 ua = *(const uint2*)(addA + (size_t)n * 128 + lc * 4);
      float t0 = -dn * a0 + bfu(ua.x & 0xffffu);
      float t1 = -dn * a1 + bfu(ua.x >> 16);
      float t2 = -dn * a2 + bfu(ua.y & 0xffffu);
      float t3 = -dn * a3 + bfu(ua.y >> 16);
      if (MODE == 1) {
        t0 = fmaxf(t0 + bias[4 * lc + 0], 0.f);
        t1 = fmaxf(t1 + bias[4 * lc + 1], 0.f);
        t2 = fmaxf(t2 + bias[4 * lc + 2], 0.f);
        t3 = fmaxf(t3 + bias[4 * lc + 3], 0.f);
        uint2 st;
        st.x = packbf2(t0, t1);
        st.y = packbf2(t2, t3);
        *(uint2*)(outb + (size_t)n * 128 + lc * 4) = st;
      } else {
        *(unsigned*)(out8 + (size_t)n * 128 + lc * 4) =
            pk_fp8x4(dn * t0, dn * t1, dn * t2, dn * t3);
      }
    }
  }
}

// edges -> float32 output region
__global__ void copy_edges_k(const int* __restrict__ ei, const int* __restrict__ flag,
                             float* __restrict__ out, int n) {
  int i = blockIdx.x * 256 + threadIdx.x;
  if (i >= n) return;
  int sh = (*flag) ? 0 : 1;
  out[i] = (float)ei[(size_t)i << sh];
}

// ---------------- launch ----------------

extern "C" void kernel_launch(void* const* d_in, const int* in_sizes, int n_in,
                              void* d_out, int out_size, void* d_ws, size_t ws_size,
                              hipStream_t stream) {
  const float* x = (const float*)d_in[0];
  const int* ei = (const int*)d_in[1];
  const float* W1 = (const float*)d_in[2];
  const float* b1 = (const float*)d_in[3];
  const float* W2 = (const float*)d_in[4];
  const float* b2 = (const float*)d_in[5];
  const float* Wl = (const float*)d_in[6];
  const float* bl = (const float*)d_in[7];
  float* outp = (float*)d_out;   // d_out is FLOAT32

  const int N = N_NODES;
  const int E = in_sizes[1] / 2;
  const int nChunk = cdiv(N, 1024);  // 98

  char* ws = (char*)d_ws;
  size_t off = 0;
  auto alloc = [&](size_t bytes) {
    off = (off + 255) & ~(size_t)255;
    size_t o = off;
    off += bytes;
    return o;
  };
  size_t o_z = alloc((size_t)(2 * N + 1) * 4);  // deg | cnt(=fillc) | flag — one memset
  int* deg = (int*)(ws + o_z);
  int* cnt = deg + N;
  int* flag = cnt + N;
  int* rowptr = (int*)(ws + alloc((size_t)(N + 1) * 4));
  int* bsum = (int*)(ws + alloc(512));
  float* dinv = (float*)(ws + alloc((size_t)N * 4));
  int2* stage = (int2*)(ws + alloc((size_t)E * 8));
  int* csr = (int*)(ws + alloc((size_t)E * 4));
  bf16* wct1 = (bf16*)(ws + alloc((size_t)384 * 192 * 2));
  bf16* wct2 = (bf16*)(ws + alloc((size_t)384 * 128 * 2));
  bf16* xp = (bf16*)(ws + alloc((size_t)N * 192 * 2));
  bf16* H = xp;  // h reuses xp (dead after gemm1)
  bf16* U0 = (bf16*)(ws + alloc((size_t)N * 128 * 2));
  bf16* U1 = (bf16*)(ws + alloc((size_t)N * 128 * 2));
  u8* G0 = (u8*)(ws + alloc((size_t)(N + 1) * 128));
  u8* G1 = (u8*)(ws + alloc((size_t)(N + 1) * 128));
  (void)ws_size;  // total ≈ 136 MB

  hipMemsetAsync(deg, 0, (size_t)(2 * N + 1) * 4, stream);

  detect_k<<<256, 256, 0, stream>>>(ei, flag);
  deg_pos_k<<<cdiv(E, 256), 256, 0, stream>>>(ei, E, flag, deg, cnt, stage);
  dinv_k<<<cdiv(N, 256), 256, 0, stream>>>(deg, dinv, N);
  scanA_k<<<nChunk, 256, 0, stream>>>(cnt, bsum, N);
  scanB_k<<<1, 128, 0, stream>>>(bsum, rowptr + N, nChunk);
  scanC_k<<<nChunk, 256, 0, stream>>>(cnt, bsum, rowptr, N);
  scatter_k<<<cdiv(E, 256), 256, 0, stream>>>(ei, E, flag, rowptr, stage, csr);

  zero_pads_k<<<1, 128, 0, stream>>>(G0, G1);
  pad_x_k<<<cdiv(N * 192, 256), 256, 0, stream>>>(x, xp);
  build_wct_k<<<cdiv(384 * 192, 256), 256, 0, stream>>>(W1, wct1, F_IN, 192);
  build_wct_k<<<cdiv(384 * 128, 256), 256, 0, stream>>>(W2, wct2, 128, 128);

  const int gm = cdiv(N, 128);
  // layer 1: Y0 -> U0 (bf16), Y1 -> U1 (bf16), Y2 -> G0 (fp8, dinv-scaled)
  gemm3_k<<<dim3(gm, 3), 256, 0, stream>>>(xp, 192, wct1, 192, U0, U1, G0, dinv, N);
  // A1 (fp8-scaled) = dinv*(P(Y2)+Y1): gather G0, add U1 -> G1
  prop_k<0><<<N / 4, 256, 0, stream>>>(rowptr, csr, G0, dinv, U1, nullptr, nullptr,
                                       nullptr, nullptr, G1, nullptr, nullptr);
  // h = relu(P(A1)+Y0+b1): gather G1, add U0 -> H (bf16)
  prop_k<1><<<N / 4, 256, 0, stream>>>(rowptr, csr, G1, dinv, U0, nullptr, b1,
                                       nullptr, nullptr, nullptr, H, nullptr);
  // layer 2 from h: Z0 -> U1, Z1 -> U0, Z2 -> G0 (fp8-scaled)
  gemm3_k<<<dim3(gm, 3), 256, 0, stream>>>(H, 128, wct2, 128, U1, U0, G0, dinv, N);
  // A2 (fp8-scaled) = dinv*(P(Z2)+Z1): gather G0, add U0 -> G1
  prop_k<0><<<N / 4, 256, 0, stream>>>(rowptr, csr, G0, dinv, U0, nullptr, nullptr,
                                       nullptr, nullptr, G1, nullptr, nullptr);
  // logits = log_softmax((P(A2)+Z0+h+b2) @ Wl + bl) -> outp[0:2N)
  prop_k<2><<<N / 4, 256, 0, stream>>>(rowptr, csr, G1, dinv, U1, H, b2,
                                       Wl, bl, nullptr, nullptr, outp);

  copy_edges_k<<<cdiv(2 * E, 256), 256, 0, stream>>>(ei, flag, outp + (size_t)2 * N, 2 * E);
}

// Round 11
// 594.506 us; speedup vs baseline: 1.1756x; 1.1756x over previous
//
#include <hip/hip_runtime.h>
#include <stdint.h>

typedef __bf16 bf16;
typedef unsigned char u8;
typedef __attribute__((ext_vector_type(8))) __bf16 bf16x8;
typedef __attribute__((ext_vector_type(4))) float f32x4;

#define N_NODES 100000
#define F_IN 165
#define NB 391     // coarse buckets of 256 nodes (391*256 = 100096 >= N)
#define NBLK 320   // blocks in bucket passes; NB*NBLK = 125120

static inline int cdiv(int a, int b) { return (a + b - 1) / b; }

__device__ __forceinline__ float bfu(unsigned hw) {
  union { unsigned u; float f; } v; v.u = hw << 16; return v.f;
}
__device__ __forceinline__ unsigned packbf2(float a, float b) {
  bf16 x = (bf16)a, y = (bf16)b;
  unsigned short sx = __builtin_bit_cast(unsigned short, x);
  unsigned short sy = __builtin_bit_cast(unsigned short, y);
  return (unsigned)sx | ((unsigned)sy << 16);
}
__device__ __forceinline__ unsigned pk_fp8x4(float a, float b, float c, float d) {
  int v = 0;
  v = __builtin_amdgcn_cvt_pk_fp8_f32(a, b, v, false);
  v = __builtin_amdgcn_cvt_pk_fp8_f32(c, d, v, true);
  return (unsigned)v;
}
__device__ __forceinline__ u8 f32_to_fp8(float v) {
  int t = __builtin_amdgcn_cvt_pk_fp8_f32(v, 0.f, 0, false);
  return (u8)(t & 0xff);
}

__device__ __forceinline__ void async16(const bf16* g, const bf16* l) {
  __builtin_amdgcn_global_load_lds(
      (const __attribute__((address_space(1))) void*)g,
      (__attribute__((address_space(3))) void*)l, 16, 0, 0);
}

// ---------------- edge dtype detection ----------------
__global__ void detect_k(const int* __restrict__ ei32, int* __restrict__ flag) {
  int i = blockIdx.x * 256 + threadIdx.x;  // 65536 samples
  int v = ei32[2 * i + 1];
  if (v != 0) atomicOr(flag, 1);
}

// ---------------- bucket-sort preprocessing (no global data atomics) ------
// sh: 1 = int64-low-words, 0 = int32

// coarse histograms of dst>>8 and src>>8, per block, column-major (bucket-major)
__global__ __launch_bounds__(256) void hist_k(const int* __restrict__ ei, int E,
                                              const int* __restrict__ flag,
                                              int* __restrict__ gcd, int* __restrict__ gcs) {
  __shared__ int hd[NB], hs[NB];
  int b = blockIdx.x, t = threadIdx.x;
  for (int i = t; i < NB; i += 256) { hd[i] = 0; hs[i] = 0; }
  __syncthreads();
  int sh = (*flag) ? 0 : 1;
  int CH = (E + NBLK - 1) / NBLK;
  int lo = b * CH, hi = min(E, lo + CH);
  for (int e = lo + t; e < hi; e += 256) {
    int s = ei[(size_t)e << sh];
    int d = ei[(size_t)(E + e) << sh];
    if ((unsigned)s < (unsigned)N_NODES && (unsigned)d < (unsigned)N_NODES && s != d) {
      atomicAdd(&hd[d >> 8], 1);
      atomicAdd(&hs[s >> 8], 1);
    }
  }
  __syncthreads();
  for (int i = t; i < NB; i += 256) {
    gcd[i * NBLK + b] = hd[i];
    gcs[i * NBLK + b] = hs[i];
  }
}

// scatter (dfine<<24 | src) into dst-bucket regions; offsets pre-reserved by scan
__global__ __launch_bounds__(256) void scat_dst_k(const int* __restrict__ ei, int E,
                                                  const int* __restrict__ flag,
                                                  const int* __restrict__ ofd,
                                                  unsigned* __restrict__ pk) {
  __shared__ int base[NB];
  int b = blockIdx.x, t = threadIdx.x;
  for (int i = t; i < NB; i += 256) base[i] = ofd[i * NBLK + b];
  __syncthreads();
  int sh = (*flag) ? 0 : 1;
  int CH = (E + NBLK - 1) / NBLK;
  int lo = b * CH, hi = min(E, lo + CH);
  for (int e = lo + t; e < hi; e += 256) {
    int s = ei[(size_t)e << sh];
    int d = ei[(size_t)(E + e) << sh];
    if ((unsigned)s < (unsigned)N_NODES && (unsigned)d < (unsigned)N_NODES && s != d) {
      int pos = atomicAdd(&base[d >> 8], 1);
      pk[pos] = ((unsigned)(d & 255) << 24) | (unsigned)s;  // s < 2^17
    }
  }
}

// scatter src into src-bucket regions (for out-degree count)
__global__ __launch_bounds__(256) void scat_src_k(const int* __restrict__ ei, int E,
                                                  const int* __restrict__ flag,
                                                  const int* __restrict__ ofs,
                                                  unsigned* __restrict__ pk2) {
  __shared__ int base[NB];
  int b = blockIdx.x, t = threadIdx.x;
  for (int i = t; i < NB; i += 256) base[i] = ofs[i * NBLK + b];
  __syncthreads();
  int sh = (*flag) ? 0 : 1;
  int CH = (E + NBLK - 1) / NBLK;
  int lo = b * CH, hi = min(E, lo + CH);
  for (int e = lo + t; e < hi; e += 256) {
    int s = ei[(size_t)e << sh];
    int d = ei[(size_t)(E + e) << sh];
    if ((unsigned)s < (unsigned)N_NODES && (unsigned)d < (unsigned)N_NODES && s != d) {
      int pos = atomicAdd(&base[s >> 8], 1);
      pk2[pos] = (unsigned)s;
    }
  }
}

// per dst-bucket: fine count + LDS scan -> rowptr; scatter src -> csr
__global__ __launch_bounds__(256) void fin_dst_k(const unsigned* __restrict__ pk,
                                                 const int* __restrict__ ofd,
                                                 const int* __restrict__ totald,
                                                 int* __restrict__ rowptr,
                                                 int* __restrict__ csr) {
  __shared__ int fh[256], fb[256];
  int b = blockIdx.x, t = threadIdx.x;
  int lo = ofd[b * NBLK];
  int hi = (b == NB - 1) ? *totald : ofd[(b + 1) * NBLK];
  fh[t] = 0;
  __syncthreads();
  for (int i = lo + t; i < hi; i += 256) atomicAdd(&fh[pk[i] >> 24], 1);
  __syncthreads();
  fb[t] = fh[t];
  __syncthreads();
  for (int offv = 1; offv < 256; offv <<= 1) {
    int x = (t >= offv) ? fb[t - offv] : 0;
    __syncthreads();
    fb[t] += x;
    __syncthreads();
  }
  int excl = fb[t] - fh[t];
  int node = b * 256 + t;
  if (node <= N_NODES) rowptr[node] = lo + excl;
  __syncthreads();
  fb[t] = lo + excl;  // running write cursor per fine bin
  __syncthreads();
  for (int i = lo + t; i < hi; i += 256) {
    unsigned v = pk[i];
    int pos = atomicAdd(&fb[v >> 24], 1);
    csr[pos] = (int)(v & 0xFFFFFFu);  // src id
  }
}

// per src-bucket: fine count -> dinv directly
__global__ __launch_bounds__(256) void fin_src_k(const unsigned* __restrict__ pk2,
                                                 const int* __restrict__ ofs,
                                                 const int* __restrict__ totals,
                                                 float* __restrict__ dinv) {
  __shared__ int fh[256];
  int b = blockIdx.x, t = threadIdx.x;
  int lo = ofs[b * NBLK];
  int hi = (b == NB - 1) ? *totals : ofs[(b + 1) * NBLK];
  fh[t] = 0;
  __syncthreads();
  for (int i = lo + t; i < hi; i += 256) atomicAdd(&fh[pk2[i] & 255], 1);
  __syncthreads();
  int node = b * 256 + t;
  if (node < N_NODES) {
    int dg = fh[t];
    dinv[node] = dg > 0 ? rsqrtf((float)dg) : 0.f;
  }
}

// ---------------- scans (generic, length nElem, in-place capable) --------

__global__ void scanA_k(const int* __restrict__ cnt, int* __restrict__ bsum, int nElem) {
  __shared__ int s[256];
  int b = blockIdx.x, t = threadIdx.x;
  int base = b * 1024;
  int sum = 0;
  for (int i = t; i < 1024; i += 256) {
    int idx = base + i;
    sum += (idx < nElem) ? cnt[idx] : 0;
  }
  s[t] = sum; __syncthreads();
  for (int off = 128; off > 0; off >>= 1) {
    if (t < off) s[t] += s[t + off];
    __syncthreads();
  }
  if (t == 0) bsum[b] = s[0];
}

__global__ void scanB_k(int* __restrict__ bsum, int* __restrict__ totalOut, int nChunk) {
  __shared__ int s[128];
  int t = threadIdx.x;
  int v = (t < nChunk) ? bsum[t] : 0;
  s[t] = v; __syncthreads();
  for (int off = 1; off < 128; off <<= 1) {
    int x = (t >= off) ? s[t - off] : 0;
    __syncthreads();
    s[t] += x;
    __syncthreads();
  }
  int excl = s[t] - v;
  if (t < nChunk) bsum[t] = excl;
  if (t == 127) *totalOut = s[127];
}

__global__ void scanC_k(const int* __restrict__ cnt, const int* __restrict__ bsum,
                        int* __restrict__ outp, int nElem) {
  __shared__ int s[256];
  int b = blockIdx.x, t = threadIdx.x;
  int base = b * 1024 + t * 4;
  int v[4]; int tot = 0;
  for (int i = 0; i < 4; i++) {
    int idx = base + i;
    v[i] = (idx < nElem) ? cnt[idx] : 0;
    tot += v[i];
  }
  s[t] = tot; __syncthreads();
  for (int off = 1; off < 256; off <<= 1) {
    int x = (t >= off) ? s[t - off] : 0;
    __syncthreads();
    s[t] += x;
    __syncthreads();
  }
  int excl = s[t] - tot + bsum[b];
  for (int i = 0; i < 4; i++) {
    int idx = base + i;
    if (idx < nElem) { outp[idx] = excl; excl += v[i]; }
  }
}

// ---------------- weight prep ----------------

__global__ void build_wct_k(const float* __restrict__ W, bf16* __restrict__ out, int Fin, int Kp) {
  int idx = blockIdx.x * 256 + threadIdx.x;
  if (idx >= 384 * Kp) return;
  int r = idx / Kp, k = idx % Kp;
  int t = r >> 7, j = r & 127;
  float v = 0.f;
  if (k < Fin) {
    if (t == 0)
      v = W[(size_t)k * 128 + j] - W[(size_t)2 * Fin * 128 + (size_t)k * 128 + j];
    else if (t == 1)
      v = W[(size_t)Fin * 128 + (size_t)k * 128 + j];
    else
      v = 2.f * W[(size_t)2 * Fin * 128 + (size_t)k * 128 + j];
  }
  out[(size_t)r * Kp + k] = (bf16)v;
}

__global__ void pad_x_k(const float* __restrict__ x, bf16* __restrict__ xp) {
  int idx = blockIdx.x * 256 + threadIdx.x;
  if (idx >= N_NODES * 192) return;
  int n = idx / 192, k = idx % 192;
  xp[idx] = (k < F_IN) ? (bf16)x[(size_t)n * F_IN + k] : (bf16)0.f;
}

__global__ void zero_pads_k(u8* __restrict__ g0, u8* __restrict__ g1) {
  int t = threadIdx.x;  // 128
  g0[(size_t)N_NODES * 128 + t] = 0;
  g1[(size_t)N_NODES * 128 + t] = 0;
}

// ---------------- GEMM: slabs y=0,1 -> bf16 C; slab y=2 -> fp8(dinv[row]*val) ----

__global__ __launch_bounds__(256) void gemm3_k(const bf16* __restrict__ A, int lda,
                                               const bf16* __restrict__ Bt, int K,
                                               bf16* __restrict__ C0, bf16* __restrict__ C1,
                                               u8* __restrict__ C2g,
                                               const float* __restrict__ dinv, int M) {
  __shared__ __align__(16) bf16 As[128 * 32];
  __shared__ __align__(16) bf16 Bs[128 * 32];
  const int tid = threadIdx.x;
  const int w = tid >> 6, l = tid & 63;
  const int mBase = blockIdx.x * 128;
  const int nb = blockIdx.y * 128;
  const int wm = (w >> 1) * 64, wn = (w & 1) * 64;
  const int lr = l & 15, lq = l >> 4;
  f32x4 acc[4][4] = {};
  for (int k0 = 0; k0 < K; k0 += 32) {
#pragma unroll
    for (int p = 0; p < 2; ++p) {
      int q = w * 2 + p;
      int row = q * 16 + (l >> 2);
      int seg = (l & 3) * 8;
      int ar = mBase + row; if (ar > M - 1) ar = M - 1;
      async16(A + (size_t)ar * lda + k0 + seg, &As[q * 512]);
      async16(Bt + (size_t)(nb + row) * K + k0 + seg, &Bs[q * 512]);
    }
    __syncthreads();
    bf16x8 a[4], b[4];
#pragma unroll
    for (int i = 0; i < 4; i++) a[i] = *(const bf16x8*)&As[(wm + i * 16 + lr) * 32 + lq * 8];
#pragma unroll
    for (int j = 0; j < 4; j++) b[j] = *(const bf16x8*)&Bs[(wn + j * 16 + lr) * 32 + lq * 8];
#pragma unroll
    for (int i = 0; i < 4; i++)
#pragma unroll
      for (int j = 0; j < 4; j++)
        acc[i][j] = __builtin_amdgcn_mfma_f32_16x16x32_bf16(a[i], b[j], acc[i][j], 0, 0, 0);
    __syncthreads();
  }
  if (blockIdx.y == 2) {
#pragma unroll
    for (int i = 0; i < 4; i++) {
#pragma unroll
      for (int r = 0; r < 4; r++) {
        int row = mBase + wm + i * 16 + lq * 4 + r;
        if (row < M) {
          float dv = dinv[row];
#pragma unroll
          for (int j = 0; j < 4; j++) {
            int col = wn + j * 16 + lr;
            C2g[(size_t)row * 128 + col] = f32_to_fp8(dv * acc[i][j][r]);
          }
        }
      }
    }
  } else {
    bf16* __restrict__ C = blockIdx.y ? C1 : C0;
#pragma unroll
    for (int i = 0; i < 4; i++) {
#pragma unroll
      for (int r = 0; r < 4; r++) {
        int row = mBase + wm + i * 16 + lq * 4 + r;
        if (row < M) {
#pragma unroll
          for (int j = 0; j < 4; j++) {
            int col = wn + j * 16 + lr;
            C[(size_t)row * 128 + col] = (bf16)acc[i][j][r];
          }
        }
      }
    }
  }
}

// ---------------- sparse propagation (fp8 unweighted gather) ----------------
// One wave per node; half-wave per edge slot; 16 edges per loop body.
// MODE 0: fp8(dinv-scaled) out. MODE 1: bf16 relu out. MODE 2: float32 logits.
template <int MODE>
__global__ __launch_bounds__(256) void prop_k(const int* __restrict__ rowptr,
                                              const int* __restrict__ csr,
                                              const u8* __restrict__ g8,
                                              const float* __restrict__ dinv,
                                              const bf16* __restrict__ addA,
                                              const bf16* __restrict__ addB,
                                              const float* __restrict__ bias,
                                              const float* __restrict__ Wl,
                                              const float* __restrict__ bl,
                                              u8* __restrict__ out8,
                                              bf16* __restrict__ outb,
                                              float* __restrict__ fout) {
  const int n = blockIdx.x * 4 + (threadIdx.x >> 6);
  const int c = threadIdx.x & 63;
  const int half = c >> 5, lc = c & 31;
  const int beg = rowptr[n], end = rowptr[n + 1];
  const u8* __restrict__ gl = g8 + lc * 4;

  float a0 = 0.f, a1 = 0.f, a2 = 0.f, a3 = 0.f;
  for (int e0 = beg; e0 < end; e0 += 16) {
    int sidx[8];
    unsigned g[8];
#pragma unroll
    for (int k = 0; k < 8; k++) {
      int idx = e0 + 2 * k + half;
      sidx[k] = (idx < end) ? csr[idx] : N_NODES;  // pad row = zeros
    }
#pragma unroll
    for (int k = 0; k < 8; k++) g[k] = *(const unsigned*)(gl + (size_t)sidx[k] * 128);
#pragma unroll
    for (int k = 0; k < 8; k++) {
      auto lo = __builtin_amdgcn_cvt_pk_f32_fp8((int)g[k], false);
      auto hi = __builtin_amdgcn_cvt_pk_f32_fp8((int)g[k], true);
      a0 += lo[0]; a1 += lo[1]; a2 += hi[0]; a3 += hi[1];
    }
  }
  const float dn = dinv[n];

  if (MODE == 2) {
    float t0 = -dn * a0, t1 = -dn * a1, t2 = -dn * a2, t3 = -dn * a3;
    if (half == 0) {
      uint2 ua = *(const uint2*)(addA + (size_t)n * 128 + lc * 4);
      uint2 uh = *(const uint2*)(addB + (size_t)n * 128 + lc * 4);
      t0 += bfu(ua.x & 0xffffu) + bfu(uh.x & 0xffffu) + bias[4 * lc + 0];
      t1 += bfu(ua.x >> 16) + bfu(uh.x >> 16) + bias[4 * lc + 1];
      t2 += bfu(ua.y & 0xffffu) + bfu(uh.y & 0xffffu) + bias[4 * lc + 2];
      t3 += bfu(ua.y >> 16) + bfu(uh.y >> 16) + bias[4 * lc + 3];
    }
    float z0 = t0 * Wl[(4 * lc + 0) * 2] + t1 * Wl[(4 * lc + 1) * 2] +
               t2 * Wl[(4 * lc + 2) * 2] + t3 * Wl[(4 * lc + 3) * 2];
    float z1 = t0 * Wl[(4 * lc + 0) * 2 + 1] + t1 * Wl[(4 * lc + 1) * 2 + 1] +
               t2 * Wl[(4 * lc + 2) * 2 + 1] + t3 * Wl[(4 * lc + 3) * 2 + 1];
#pragma unroll
    for (int off = 32; off > 0; off >>= 1) {
      z0 += __shfl_down(z0, off);
      z1 += __shfl_down(z1, off);
    }
    if (c == 0) {
      z0 += bl[0];
      z1 += bl[1];
      float m = fmaxf(z0, z1);
      float lse = m + logf(expf(z0 - m) + expf(z1 - m));
      fout[(size_t)n * 2 + 0] = z0 - lse;
      fout[(size_t)n * 2 + 1] = z1 - lse;
    }
  } else {
    a0 += __shfl_down(a0, 32);
    a1 += __shfl_down(a1, 32);
    a2 += __shfl_down(a2, 32);
    a3 += __shfl_down(a3, 32);
    if (half == 0) {
      uint2 ua = *(const uint2*)(addA + (size_t)n * 128 + lc * 4);
      float t0 = -dn * a0 + bfu(ua.x & 0xffffu);
      float t1 = -dn * a1 + bfu(ua.x >> 16);
      float t2 = -dn * a2 + bfu(ua.y & 0xffffu);
      float t3 = -dn * a3 + bfu(ua.y >> 16);
      if (MODE == 1) {
        t0 = fmaxf(t0 + bias[4 * lc + 0], 0.f);
        t1 = fmaxf(t1 + bias[4 * lc + 1], 0.f);
        t2 = fmaxf(t2 + bias[4 * lc + 2], 0.f);
        t3 = fmaxf(t3 + bias[4 * lc + 3], 0.f);
        uint2 st;
        st.x = packbf2(t0, t1);
        st.y = packbf2(t2, t3);
        *(uint2*)(outb + (size_t)n * 128 + lc * 4) = st;
      } else {
        *(unsigned*)(out8 + (size_t)n * 128 + lc * 4) =
            pk_fp8x4(dn * t0, dn * t1, dn * t2, dn * t3);
      }
    }
  }
}

// edges -> float32 output region
__global__ void copy_edges_k(const int* __restrict__ ei, const int* __restrict__ flag,
                             float* __restrict__ out, int n) {
  int i = blockIdx.x * 256 + threadIdx.x;
  if (i >= n) return;
  int sh = (*flag) ? 0 : 1;
  out[i] = (float)ei[(size_t)i << sh];
}

// ---------------- launch ----------------

extern "C" void kernel_launch(void* const* d_in, const int* in_sizes, int n_in,
                              void* d_out, int out_size, void* d_ws, size_t ws_size,
                              hipStream_t stream) {
  const float* x = (const float*)d_in[0];
  const int* ei = (const int*)d_in[1];
  const float* W1 = (const float*)d_in[2];
  const float* b1 = (const float*)d_in[3];
  const float* W2 = (const float*)d_in[4];
  const float* b2 = (const float*)d_in[5];
  const float* Wl = (const float*)d_in[6];
  const float* bl = (const float*)d_in[7];
  float* outp = (float*)d_out;

  const int N = N_NODES;
  const int E = in_sizes[1] / 2;
  const int L = NB * NBLK;                 // 125120
  const int nChunkS = cdiv(L, 1024);       // 123

  char* ws = (char*)d_ws;
  size_t off = 0;
  auto alloc = [&](size_t bytes) {
    off = (off + 255) & ~(size_t)255;
    size_t o = off;
    off += bytes;
    return o;
  };
  int* flag = (int*)(ws + alloc(4));
  int* gcd = (int*)(ws + alloc((size_t)L * 4));
  int* gcs = (int*)(ws + alloc((size_t)L * 4));
  int* bsum = (int*)(ws + alloc(512));
  int* totald = (int*)(ws + alloc(4));
  int* totals = (int*)(ws + alloc(4));
  int* rowptr = (int*)(ws + alloc((size_t)(N + 1) * 4));
  float* dinv = (float*)(ws + alloc((size_t)N * 4));
  unsigned* pk = (unsigned*)(ws + alloc((size_t)E * 4));
  unsigned* pk2 = (unsigned*)(ws + alloc((size_t)E * 4));
  int* csr = (int*)(ws + alloc((size_t)E * 4));
  bf16* wct1 = (bf16*)(ws + alloc((size_t)384 * 192 * 2));
  bf16* wct2 = (bf16*)(ws + alloc((size_t)384 * 128 * 2));
  bf16* xp = (bf16*)(ws + alloc((size_t)N * 192 * 2));
  bf16* H = xp;  // h reuses xp (dead after gemm1)
  bf16* U0 = (bf16*)(ws + alloc((size_t)N * 128 * 2));
  bf16* U1 = (bf16*)(ws + alloc((size_t)N * 128 * 2));
  u8* G0 = (u8*)(ws + alloc((size_t)(N + 1) * 128));
  u8* G1 = (u8*)(ws + alloc((size_t)(N + 1) * 128));
  (void)ws_size;  // total ~ 140 MB

  hipMemsetAsync(flag, 0, 4, stream);
  detect_k<<<256, 256, 0, stream>>>(ei, flag);

  // ---- bucket-sort CSR + degree (no global data atomics) ----
  hist_k<<<NBLK, 256, 0, stream>>>(ei, E, flag, gcd, gcs);
  scanA_k<<<nChunkS, 256, 0, stream>>>(gcd, bsum, L);
  scanB_k<<<1, 128, 0, stream>>>(bsum, totald, nChunkS);
  scanC_k<<<nChunkS, 256, 0, stream>>>(gcd, bsum, gcd, L);
  scanA_k<<<nChunkS, 256, 0, stream>>>(gcs, bsum, L);
  scanB_k<<<1, 128, 0, stream>>>(bsum, totals, nChunkS);
  scanC_k<<<nChunkS, 256, 0, stream>>>(gcs, bsum, gcs, L);
  scat_dst_k<<<NBLK, 256, 0, stream>>>(ei, E, flag, gcd, pk);
  scat_src_k<<<NBLK, 256, 0, stream>>>(ei, E, flag, gcs, pk2);
  fin_dst_k<<<NB, 256, 0, stream>>>(pk, gcd, totald, rowptr, csr);
  fin_src_k<<<NB, 256, 0, stream>>>(pk2, gcs, totals, dinv);

  zero_pads_k<<<1, 128, 0, stream>>>(G0, G1);
  pad_x_k<<<cdiv(N * 192, 256), 256, 0, stream>>>(x, xp);
  build_wct_k<<<cdiv(384 * 192, 256), 256, 0, stream>>>(W1, wct1, F_IN, 192);
  build_wct_k<<<cdiv(384 * 128, 256), 256, 0, stream>>>(W2, wct2, 128, 128);

  const int gm = cdiv(N, 128);
  // layer 1: Y0 -> U0 (bf16), Y1 -> U1 (bf16), Y2 -> G0 (fp8, dinv-scaled)
  gemm3_k<<<dim3(gm, 3), 256, 0, stream>>>(xp, 192, wct1, 192, U0, U1, G0, dinv, N);
  prop_k<0><<<N / 4, 256, 0, stream>>>(rowptr, csr, G0, dinv, U1, nullptr, nullptr,
                                       nullptr, nullptr, G1, nullptr, nullptr);
  prop_k<1><<<N / 4, 256, 0, stream>>>(rowptr, csr, G1, dinv, U0, nullptr, b1,
                                       nullptr, nullptr, nullptr, H, nullptr);
  gemm3_k<<<dim3(gm, 3), 256, 0, stream>>>(H, 128, wct2, 128, U1, U0, G0, dinv, N);
  prop_k<0><<<N / 4, 256, 0, stream>>>(rowptr, csr, G0, dinv, U0, nullptr, nullptr,
                                       nullptr, nullptr, G1, nullptr, nullptr);
  prop_k<2><<<N / 4, 256, 0, stream>>>(rowptr, csr, G1, dinv, U1, H, b2,
                                       Wl, bl, nullptr, nullptr, outp);

  copy_edges_k<<<cdiv(2 * E, 256), 256, 0, stream>>>(ei, flag, outp + (size_t)2 * N, 2 * E);
}